// Round 7
// baseline (11210.316 us; speedup 1.0000x reference)
//
#include <hip/hip_runtime.h>
#include <hip/hip_bf16.h>

#define BATCH 2048
#define SEQ   80
#define EMBD  100
#define HU    512
#define NG    2048

typedef short bf16x8 __attribute__((ext_vector_type(8)));
typedef float f32x4  __attribute__((ext_vector_type(4)));
typedef int   i32x4  __attribute__((ext_vector_type(4)));

#define AS1(p) ((const __attribute__((address_space(1))) void*)(p))
#define AS3(p) ((__attribute__((address_space(3))) void*)(p))
#define GLL(src, dst, aux) __builtin_amdgcn_global_load_lds(AS1(src), AS3(dst), 16, 0, aux)

// ---------------- prep kernels (proven, unchanged) ----------------
__global__ __launch_bounds__(256) void prep_emb(const float* __restrict__ emb,
                                                __hip_bfloat16* __restrict__ embp)
{
    int idx = blockIdx.x*256 + threadIdx.x;
    int row = idx >> 7, k = idx & 127;
    embp[idx] = __float2bfloat16(k < EMBD ? emb[row*EMBD + k] : 0.f);
}

// Gate-interleaved transposed weights. n = u*4 + g, col_orig = g*512 + u.
__global__ __launch_bounds__(256) void prep_wt(
    const float* __restrict__ W1, const float* __restrict__ U1, const float* __restrict__ b1,
    const float* __restrict__ W2, const float* __restrict__ U2, const float* __restrict__ b2,
    __hip_bfloat16* __restrict__ wt1, __hip_bfloat16* __restrict__ wt2,
    float* __restrict__ bp1, float* __restrict__ bp2)
{
    const int n = blockIdx.x;
    const int u = n >> 2, g = n & 3, col = g*HU + u;
    if (blockIdx.y == 0) {
        for (int k = threadIdx.x; k < 640; k += 256) {
            float v = (k < EMBD) ? W1[k*NG + col] : ((k < 128) ? 0.f : U1[(k-128)*NG + col]);
            wt1[n*640 + k] = __float2bfloat16(v);
        }
        if (threadIdx.x == 0) bp1[n] = b1[col];
    } else {
        for (int k = threadIdx.x; k < 1024; k += 256) {
            float v = (k < HU) ? W2[k*NG + col] : U2[(k-HU)*NG + col];
            wt2[n*1024 + k] = __float2bfloat16(v);
        }
        if (threadIdx.x == 0) bp2[n] = b2[col];
    }
}

// ---------------- persistent LSTM, batch-split across XCDs ----------------
// XCD x owns batch rows [x*256, x*256+256): h1/h2/c stay XCD-local (L2-coherent via
// plain store + sc0 read). Weights streamed from L3 each round (L3 holds all 6.8MB).
// 256 blocks, 512 thr, 1 block/CU (LDS ~111KB). Slot in XCD: mb(2) x nb(16),
// block tile 128 rows x 128 gate-cols. 8 waves = mp(2) x np(2) x kq(2) K-split.
__global__ __launch_bounds__(512, 1) void lstm_persist(
    const int* __restrict__ ids,
    const __hip_bfloat16* __restrict__ embp,
    const __hip_bfloat16* __restrict__ wt1, const float* __restrict__ bp1,
    const __hip_bfloat16* __restrict__ wt2, const float* __restrict__ bp2,
    __hip_bfloat16* __restrict__ h1a, __hip_bfloat16* __restrict__ h1b,
    __hip_bfloat16* __restrict__ h2a, __hip_bfloat16* __restrict__ h2b,
    unsigned long long* __restrict__ xbars,   // [8] padded 64B apart
    unsigned* __restrict__ slotctr)           // [8]
{
    // LDS layout (bytes):
    // [0, 64K)  : staging, 2 bufs x 4 tiles(Alo,Ahi,Blo,Bhi) x 8KB
    // [0, 65K)  : (overlay) K-split reduce, 4 pos x [64][65] f32
    // [69632,.) : hs h-stage [128][40] ushort (10KB)
    // [79872,.) : c1 [128][33] f32 ; [96768,.) : c2  -> total 113664
    __shared__ __align__(16) char smem[113664];
    __shared__ int s_info;

    unsigned short* stg = (unsigned short*)smem;
    unsigned short* hs  = (unsigned short*)(smem + 69632);
    float* cls1 = (float*)(smem + 79872);
    float* cls2 = (float*)(smem + 96768);

    const int tid = threadIdx.x;
    if (tid == 0) {
        unsigned x = __builtin_amdgcn_s_getreg(63508) & 7u;   // HW_REG_XCC_ID
        unsigned s = atomicAdd(&slotctr[x], 1u);
        s_info = (int)((x << 8) | (s & 31u));
    }
    // zero cell state
    for (int i = tid; i < 2*128*33; i += 512) ((float*)(smem + 79872))[i] = 0.f;
    __syncthreads();
    const int xcd  = (s_info >> 8) & 7;
    const int slot = s_info & 31;
    const int mb = slot >> 4, nb = slot & 15;
    const int m0g = xcd*256 + mb*128;     // global batch-row base
    const int n0  = nb*128;               // gate-col base

    const int w = tid >> 6, lane = tid & 63;
    const int l15 = lane & 15, tq = lane >> 4;
    const int kq = w >> 2, mp = (w >> 1) & 1, np = w & 1;
    const int rowlane = w*16 + l15;       // staging row 0..127
    const int growA = m0g + rowlane;      // global batch row this lane stages
    const int gcolB = n0 + rowlane;       // weight row this lane stages
    const int koff = tq*8;

    unsigned long long* xb = &xbars[xcd*8];

    f32x4 acc[4][4];

    auto dstp = [&](int buf, int T) -> unsigned short* {
        return stg + buf*16384 + T*4096 + w*512;
    };

    auto compute = [&](int buf){
        const unsigned short* Ab = stg + buf*16384 + kq*4096;
        const unsigned short* Bb = stg + buf*16384 + 8192 + kq*4096;
        bf16x8 aF[4], bF[4];
        #pragma unroll
        for (int mi = 0; mi < 4; ++mi)
            aF[mi] = *(const bf16x8*)&Ab[(mp*4+mi)*512 + tq*128 + l15*8];
        #pragma unroll
        for (int ni = 0; ni < 4; ++ni)
            bF[ni] = *(const bf16x8*)&Bb[(np*4+ni)*512 + tq*128 + l15*8];
        #pragma unroll
        for (int mi = 0; mi < 4; ++mi)
            #pragma unroll
            for (int ni = 0; ni < 4; ++ni)
                acc[mi][ni] = __builtin_amdgcn_mfma_f32_16x16x32_bf16(aF[mi], bF[ni], acc[mi][ni], 0, 0, 0);
    };

    // K-split reduce + fused gate epilogue + coherent h store
    auto redepi = [&](const float* bp, float* cl, __hip_bfloat16* hdst){
        const int pos = mp*2 + np;
        float* rp = (float*)smem + pos*(64*65);
        if (kq == 1) {
            #pragma unroll
            for (int mi = 0; mi < 4; ++mi)
                #pragma unroll
                for (int ni = 0; ni < 4; ++ni)
                    #pragma unroll
                    for (int rr = 0; rr < 4; ++rr)
                        rp[(mi*16 + tq*4 + rr)*65 + ni*16 + l15] = acc[mi][ni][rr];
        }
        __syncthreads();
        if (kq == 0) {
            const int gq = lane & 3;
            const bool isT = (gq == 2);
            #pragma unroll
            for (int ni = 0; ni < 4; ++ni) {
                const int ncl = np*64 + ni*16 + l15;
                const float bv = bp[n0 + ncl];
                const int ul = ncl >> 2;
                #pragma unroll
                for (int mi = 0; mi < 4; ++mi) {
                    #pragma unroll
                    for (int rr = 0; rr < 4; ++rr) {
                        const int rowl = mp*64 + mi*16 + tq*4 + rr;
                        const float z = acc[mi][ni][rr]
                                      + rp[(mi*16 + tq*4 + rr)*65 + ni*16 + l15] + bv;
                        const float zz = isT ? 2.f*z : z;
                        const float sg = 1.f/(1.f + __expf(-zz));
                        const float act = isT ? fmaf(2.f, sg, -1.f) : sg;  // tanh via sigm
                        const float act2 = __shfl_xor(act, 2);   // i<->g, f<->o
                        const float pig  = act * act2;           // gq0: sig(i)*tanh(g)
                        const float pig1 = __shfl_xor(pig, 1);   // gq1 <- gq0
                        const float c_old = cl[rowl*33 + ul];
                        const float cn  = fmaf(act, c_old, pig1);          // gq1
                        const float tcn = fmaf(2.f, 1.f/(1.f + __expf(-2.f*cn)), -1.f);
                        const float tcn2 = __shfl_xor(tcn, 2);   // gq3 <- gq1
                        const float hv  = act * tcn2;            // gq3: sig(o)*tanh(c)
                        if (gq == 1) cl[rowl*33 + ul] = cn;
                        if (gq == 3) {
                            __hip_bfloat16 hb = __float2bfloat16(hv);
                            hs[rowl*40 + ul] = *(unsigned short*)&hb;
                        }
                    }
                }
            }
        }
        __syncthreads();
        {   // 8KB h slice -> global (plain store: lands in own-XCD L2)
            const int row = tid >> 2, ch = tid & 3;
            i32x4 v = *(const i32x4*)&hs[row*40 + ch*8];
            *(i32x4*)(hdst + (size_t)(m0g + row)*HU + (n0 >> 2) + ch*8) = v;
        }
    };

    // XCD-local barrier (32 blocks), relaxed u64 {gen,cnt}, no cache maintenance
    auto bar = [&](){
        asm volatile("s_waitcnt vmcnt(0)" ::: "memory");
        __syncthreads();
        if (tid == 0) {
            unsigned long long old = __hip_atomic_fetch_add(xb, 1ull,
                                        __ATOMIC_RELAXED, __HIP_MEMORY_SCOPE_AGENT);
            unsigned g = (unsigned)(old >> 32);
            if ((unsigned)(old & 0xffffffffull) == 31u)
                __hip_atomic_fetch_add(xb, (1ull << 32) - 32ull,
                                       __ATOMIC_RELAXED, __HIP_MEMORY_SCOPE_AGENT);
            else
                while ((unsigned)(__hip_atomic_load(xb, __ATOMIC_RELAXED,
                                        __HIP_MEMORY_SCOPE_AGENT) >> 32) == g)
                    __builtin_amdgcn_s_sleep(8);
        }
        __syncthreads();
        asm volatile("" ::: "memory");
    };

    for (int r = 0; r <= SEQ; ++r) {
        const __hip_bfloat16* h1p = ((r-1)&1) ? h1b : h1a;   // h1[t=r-1]
        __hip_bfloat16*       h1c = (r&1)     ? h1b : h1a;   // h1[t=r]
        const __hip_bfloat16* h2c = (r&1)     ? h2b : h2a;   // h2[t=r-2]
        __hip_bfloat16*       h2p = ((r-1)&1) ? h2b : h2a;   // h2[t=r-1]

        if (r < SEQ) {
            // ---- Layer 1: t=r, K=640 (embp 0..127 | h1p 128..639), K-split 320/320 ----
            #pragma unroll
            for (int mi = 0; mi < 4; ++mi)
                #pragma unroll
                for (int ni = 0; ni < 4; ++ni) acc[mi][ni] = (f32x4){0.f,0.f,0.f,0.f};
            const int myid = ids[growA*SEQ + r];
            const __hip_bfloat16* eb = embp + (size_t)myid*128 + koff;
            const __hip_bfloat16* hb1 = h1p + (size_t)growA*HU;
            const __hip_bfloat16* wb = wt1 + (size_t)gcolB*640;

            GLL(eb,                 dstp(0,0), 0);
            GLL(hb1 + 192 + koff,   dstp(0,1), 1);   // khi=320 -> h1[192]
            GLL(wb + koff,          dstp(0,2), 0);
            GLL(wb + 320 + koff,    dstp(0,3), 0);
            __syncthreads();
            #pragma unroll
            for (int i = 0; i < 10; ++i) {
                const int b = i & 1;
                if (i + 1 < 10) {
                    const int klo = (i+1)*32 + koff;
                    if (i + 1 < 4) GLL(eb + (i+1)*32,        dstp(b^1,0), 0);
                    else           GLL(hb1 + (klo - 128),    dstp(b^1,0), 1);
                    GLL(hb1 + (192 + (i+1)*32 + koff),       dstp(b^1,1), 1);
                    GLL(wb + klo,                            dstp(b^1,2), 0);
                    GLL(wb + (320 + (i+1)*32 + koff),        dstp(b^1,3), 0);
                }
                compute(b);
                __syncthreads();
            }
            redepi(bp1, cls1, h1c);
        }

        if (r >= 1) {
            // ---- Layer 2: t=r-1, K=1024 (h1p 0..511 | h2c 512..1023), K-split 512/512 ----
            #pragma unroll
            for (int mi = 0; mi < 4; ++mi)
                #pragma unroll
                for (int ni = 0; ni < 4; ++ni) acc[mi][ni] = (f32x4){0.f,0.f,0.f,0.f};
            const __hip_bfloat16* hb1 = h1p + (size_t)growA*HU;
            const __hip_bfloat16* hb2 = h2c + (size_t)growA*HU;
            const __hip_bfloat16* wb = wt2 + (size_t)gcolB*1024;

            GLL(hb1 + koff,         dstp(0,0), 1);
            GLL(hb2 + koff,         dstp(0,1), 1);
            GLL(wb + koff,          dstp(0,2), 0);
            GLL(wb + 512 + koff,    dstp(0,3), 0);
            __syncthreads();
            #pragma unroll
            for (int i = 0; i < 16; ++i) {
                const int b = i & 1;
                if (i + 1 < 16) {
                    const int ko = (i+1)*32 + koff;
                    GLL(hb1 + ko,           dstp(b^1,0), 1);
                    GLL(hb2 + ko,           dstp(b^1,1), 1);
                    GLL(wb + ko,            dstp(b^1,2), 0);
                    GLL(wb + 512 + ko,      dstp(b^1,3), 0);
                }
                compute(b);
                __syncthreads();
            }
            redepi(bp2, cls2, h2p);
        }
        bar();
    }
}

// out[b] = sigmoid(h2[b,:] @ Wd + bd)
__global__ __launch_bounds__(256) void head_k(const __hip_bfloat16* __restrict__ h2,
    const float* __restrict__ Wd, const float* __restrict__ bd, float* __restrict__ out)
{
    const int b = blockIdx.x*4 + (threadIdx.x >> 6);
    const int lane = threadIdx.x & 63;
    float s = 0.f;
    #pragma unroll
    for (int u = lane; u < HU; u += 64) s += __bfloat162float(h2[b*HU + u]) * Wd[u];
    #pragma unroll
    for (int off = 32; off > 0; off >>= 1) s += __shfl_xor(s, off);
    if (lane == 0) out[b] = 1.f/(1.f + __expf(-(s + bd[0])));
}

extern "C" void kernel_launch(void* const* d_in, const int* in_sizes, int n_in,
                              void* d_out, int out_size, void* d_ws, size_t ws_size,
                              hipStream_t stream)
{
    const int*   ids = (const int*)  d_in[0];
    const float* emb = (const float*)d_in[1];
    const float* W1  = (const float*)d_in[2];
    const float* U1  = (const float*)d_in[3];
    const float* b1  = (const float*)d_in[4];
    const float* W2  = (const float*)d_in[5];
    const float* U2  = (const float*)d_in[6];
    const float* b2  = (const float*)d_in[7];
    const float* Wd  = (const float*)d_in[8];
    const float* bd  = (const float*)d_in[9];
    float* out = (float*)d_out;

    const size_t HS = (size_t)BATCH*HU;
    char* p = (char*)d_ws;
    unsigned long long* xbars = (unsigned long long*)p;        // 8 x 64B apart
    unsigned*           slotc = (unsigned*)(p + 512);          // 8
    p += 1024;
    __hip_bfloat16* h1a = (__hip_bfloat16*)p;  p += HS*2;
    __hip_bfloat16* h1b = (__hip_bfloat16*)p;  p += HS*2;
    __hip_bfloat16* h2a = (__hip_bfloat16*)p;  p += HS*2;
    __hip_bfloat16* h2b = (__hip_bfloat16*)p;  p += HS*2;
    __hip_bfloat16* embp = (__hip_bfloat16*)p; p += (size_t)10000*128*2;
    __hip_bfloat16* wt1  = (__hip_bfloat16*)p; p += (size_t)2048*640*2;
    __hip_bfloat16* wt2  = (__hip_bfloat16*)p; p += (size_t)2048*1024*2;
    float* bp1 = (float*)p;                    p += 2048*4;
    float* bp2 = (float*)p;                    p += 2048*4;

    // zero barriers + slot counters + all h buffers (replay-safe, deterministic)
    hipMemsetAsync(d_ws, 0, 1024 + 4*HS*2, stream);

    prep_emb<<<10000*128/256, 256, 0, stream>>>(emb, embp);
    prep_wt<<<dim3(2048,2), 256, 0, stream>>>(W1,U1,b1,W2,U2,b2, wt1,wt2,bp1,bp2);

    lstm_persist<<<256, 512, 0, stream>>>(ids, embp, wt1, bp1, wt2, bp2,
                                          h1a, h1b, h2a, h2b, xbars, slotc);

    // h2[t=79] written at r=80 into h2[(80-1)&1] = h2b
    head_k<<<BATCH/4, 256, 0, stream>>>(h2b, Wd, bd, out);
}

// Round 8
// 4353.794 us; speedup vs baseline: 2.5748x; 2.5748x over previous
//
#include <hip/hip_runtime.h>
#include <hip/hip_bf16.h>

#define BATCH 2048
#define SEQ   80
#define EMBD  100
#define HU    512
#define NG    2048

typedef short bf16x8 __attribute__((ext_vector_type(8)));
typedef float f32x4  __attribute__((ext_vector_type(4)));
typedef int   i32x4  __attribute__((ext_vector_type(4)));

#define AS1(p) ((const __attribute__((address_space(1))) void*)(p))
#define AS3(p) ((__attribute__((address_space(3))) void*)(p))
#define GLL(src, dst, aux) __builtin_amdgcn_global_load_lds(AS1(src), AS3(dst), 16, 0, aux)

// ---------------- prep kernels (proven, unchanged) ----------------
__global__ __launch_bounds__(256) void prep_emb(const float* __restrict__ emb,
                                                __hip_bfloat16* __restrict__ embp)
{
    int idx = blockIdx.x*256 + threadIdx.x;
    int row = idx >> 7, k = idx & 127;
    embp[idx] = __float2bfloat16(k < EMBD ? emb[row*EMBD + k] : 0.f);
}

// Gate-interleaved transposed weights. n = u*4 + g, col_orig = g*512 + u.
__global__ __launch_bounds__(256) void prep_wt(
    const float* __restrict__ W1, const float* __restrict__ U1, const float* __restrict__ b1,
    const float* __restrict__ W2, const float* __restrict__ U2, const float* __restrict__ b2,
    __hip_bfloat16* __restrict__ wt1, __hip_bfloat16* __restrict__ wt2,
    float* __restrict__ bp1, float* __restrict__ bp2)
{
    const int n = blockIdx.x;
    const int u = n >> 2, g = n & 3, col = g*HU + u;
    if (blockIdx.y == 0) {
        for (int k = threadIdx.x; k < 640; k += 256) {
            float v = (k < EMBD) ? W1[k*NG + col] : ((k < 128) ? 0.f : U1[(k-128)*NG + col]);
            wt1[n*640 + k] = __float2bfloat16(v);
        }
        if (threadIdx.x == 0) bp1[n] = b1[col];
    } else {
        for (int k = threadIdx.x; k < 1024; k += 256) {
            float v = (k < HU) ? W2[k*NG + col] : U2[(k-HU)*NG + col];
            wt2[n*1024 + k] = __float2bfloat16(v);
        }
        if (threadIdx.x == 0) bp2[n] = b2[col];
    }
}

// ---------------- persistent LSTM: batch-split XCDs, wt2-in-LDS ----------------
// XCD x owns rows [256x,256x+256). 32 blocks/XCD = 32 col-groups of 64 gate-cols.
// Block tile 256r x 64c, 8 waves = 4M(64r) x 2N(32c). wt2 K0..895 LDS-resident;
// wt1 + wt2-tail stream from XCD-L2 (resident: 2.6MB wt1 + 1MB h < 4MB).
// h coherence: plain store -> own L2; read via GLL aux=1 (L1 bypass, L2 hit).
__global__ __launch_bounds__(512, 1) void lstm_persist(
    const int* __restrict__ ids,
    const __hip_bfloat16* __restrict__ embp,
    const __hip_bfloat16* __restrict__ wt1, const float* __restrict__ bp1,
    const __hip_bfloat16* __restrict__ wt2, const float* __restrict__ bp2,
    __hip_bfloat16* __restrict__ h1a, __hip_bfloat16* __restrict__ h1b,
    __hip_bfloat16* __restrict__ h2a, __hip_bfloat16* __restrict__ h2b,
    unsigned long long* __restrict__ xbars,   // [8] spaced 64B
    unsigned* __restrict__ slotctr)           // [8]
{
    __shared__ __align__(16) char wt2s_[114688];   // 28 K-tiles x 4KB (K 0..895)
    __shared__ __align__(16) char stg_[40960];     // 2 bufs x (A 16KB + B 4KB)
    __shared__ int s_info;

    const int tid = threadIdx.x;
    if (tid == 0) {
        unsigned x = __builtin_amdgcn_s_getreg(63508) & 7u;   // HW_REG_XCC_ID
        unsigned s = atomicAdd(&slotctr[x], 1u);
        s_info = (int)((x << 8) | (s & 31u));
    }
    __syncthreads();
    const int xcd = (s_info >> 8) & 7;
    const int cg  = s_info & 31;
    const int m0g = xcd * 256;            // batch-row base (XCD-local)
    const int n0  = cg * 64;              // gate-col base

    const int w = tid >> 6, lane = tid & 63;
    const int l15 = lane & 15, tq = lane >> 4;
    const int wM = w >> 1, wN = w & 1;    // wave tile: rows wM*64+, cols wN*32+

    unsigned long long* xb = &xbars[xcd*8];

    f32x4 acc[4][2];
    float c1r[4][2][4] = {};              // cell state (live on gq==1 lanes)
    float c2r[4][2][4] = {};

    // ---- load wt2 K0..895 into LDS once (chunk layout [kt][c16cols][tq][l15]) ----
    #pragma unroll
    for (int i = 0; i < 14; ++i) {
        const int idx = w + i*8;          // 0..111 = 28 tiles x 4 chunks
        const int kt = idx >> 2, c = idx & 3;
        GLL(wt2 + (size_t)(n0 + c*16 + l15)*1024 + kt*32 + tq*8,
            wt2s_ + kt*4096 + c*1024, 0);
    }

    auto zacc = [&](){
        #pragma unroll
        for (int mi = 0; mi < 4; ++mi)
            #pragma unroll
            for (int ni = 0; ni < 2; ++ni) acc[mi][ni] = (f32x4){0.f,0.f,0.f,0.f};
    };
    auto stgA = [&](int buf) -> char* { return stg_ + buf*20480; };
    auto stgB = [&](int buf) -> char* { return stg_ + buf*20480 + 16384; };

    // A tile 256r x 32K: 16 chunks of 16 rows; thread stages chunks w*2, w*2+1
    auto stageA = [&](const __hip_bfloat16* rowbase, int koff, int buf, bool coh){
        #pragma unroll
        for (int j = 0; j < 2; ++j) {
            const int c = w*2 + j;
            const __hip_bfloat16* src = rowbase + (size_t)(c*16 + l15)*HU + koff + tq*8;
            if (coh) GLL(src, stgA(buf) + c*1024, 1);   // L1-bypass (fresh from L2)
            else     GLL(src, stgA(buf) + c*1024, 0);
        }
    };
    auto stageA_emb = [&](int id0, int id1, int koff, int buf){
        GLL(embp + (size_t)id0*128 + koff + tq*8, stgA(buf) + (w*2  )*1024, 0);
        GLL(embp + (size_t)id1*128 + koff + tq*8, stgA(buf) + (w*2+1)*1024, 0);
    };
    // B tile 64c x 32K: 4 chunks, staged by waves 0..3
    auto stageBt = [&](const __hip_bfloat16* wt, int KTOT, int koff, int buf){
        if (w < 4)
            GLL(wt + (size_t)(n0 + w*16 + l15)*KTOT + koff + tq*8,
                stgB(buf) + w*1024, 0);
    };

    auto compute = [&](const char* Ab, const char* Bb){
        bf16x8 aF[4], bF[2];
        #pragma unroll
        for (int mi = 0; mi < 4; ++mi)
            aF[mi] = *(const bf16x8*)(Ab + (wM*4+mi)*1024 + tq*256 + l15*16);
        #pragma unroll
        for (int ni = 0; ni < 2; ++ni)
            bF[ni] = *(const bf16x8*)(Bb + (wN*2+ni)*1024 + tq*256 + l15*16);
        #pragma unroll
        for (int mi = 0; mi < 4; ++mi)
            #pragma unroll
            for (int ni = 0; ni < 2; ++ni)
                acc[mi][ni] = __builtin_amdgcn_mfma_f32_16x16x32_bf16(
                                  aF[mi], bF[ni], acc[mi][ni], 0, 0, 0);
    };

    // gates epilogue: 4-lane group = {i,f,g,o} of one unit; c in regs; h via LDS stage
    auto epilogue = [&](const float* bp, float (&cr)[4][2][4], __hip_bfloat16* hdst){
        unsigned short* hsp = (unsigned short*)stg_;   // [256 rows][16 units]
        const int gq = l15 & 3;
        const bool isT = (gq == 2);
        #pragma unroll
        for (int ni = 0; ni < 2; ++ni) {
            const int nl = wN*32 + ni*16 + l15;
            const float bv = bp[n0 + nl];
            const int ul = nl >> 2;
            #pragma unroll
            for (int mi = 0; mi < 4; ++mi) {
                #pragma unroll
                for (int rr = 0; rr < 4; ++rr) {
                    const int rowl = wM*64 + mi*16 + tq*4 + rr;
                    const float z  = acc[mi][ni][rr] + bv;
                    const float zz = isT ? 2.f*z : z;
                    const float sg = 1.f/(1.f + __expf(-zz));
                    const float act = isT ? fmaf(2.f, sg, -1.f) : sg;   // tanh via sigm
                    const float act2 = __shfl_xor(act, 2);    // i<->g, f<->o
                    const float pig  = act * act2;            // gq0: sig(i)*tanh(g)
                    const float pig1 = __shfl_xor(pig, 1);    // gq1 <- gq0
                    const float cn  = fmaf(act, cr[mi][ni][rr], pig1);  // gq1
                    const float tcn = fmaf(2.f, 1.f/(1.f + __expf(-2.f*cn)), -1.f);
                    const float tcn2 = __shfl_xor(tcn, 2);    // gq3 <- gq1
                    const float hv  = act * tcn2;             // gq3: sig(o)*tanh(c)
                    if (gq == 1) cr[mi][ni][rr] = cn;
                    if (gq == 3) {
                        __hip_bfloat16 hb = __float2bfloat16(hv);
                        hsp[rowl*16 + ul] = *(unsigned short*)&hb;
                    }
                }
            }
        }
        __syncthreads();
        {   // 8KB h slice -> global plain store (lands in own-XCD L2)
            const int row = tid >> 1, uo = (tid & 1)*8;
            i32x4 v = *(const i32x4*)(hsp + row*16 + uo);
            *(i32x4*)(hdst + (size_t)(m0g + row)*HU + (n0 >> 2) + uo) = v;
        }
        __syncthreads();   // hsp free before next staging overwrites it
    };

    // XCD-local barrier (32 blocks), relaxed u64 {gen,cnt} — no cache maintenance
    auto bar = [&](){
        asm volatile("s_waitcnt vmcnt(0)" ::: "memory");
        __syncthreads();
        if (tid == 0) {
            unsigned long long old = __hip_atomic_fetch_add(xb, 1ull,
                                        __ATOMIC_RELAXED, __HIP_MEMORY_SCOPE_AGENT);
            unsigned g = (unsigned)(old >> 32);
            if ((unsigned)(old & 0xffffffffull) == 31u)
                __hip_atomic_fetch_add(xb, (1ull << 32) - 32ull,
                                       __ATOMIC_RELAXED, __HIP_MEMORY_SCOPE_AGENT);
            else
                while ((unsigned)(__hip_atomic_load(xb, __ATOMIC_RELAXED,
                                        __HIP_MEMORY_SCOPE_AGENT) >> 32) == g)
                    __builtin_amdgcn_s_sleep(8);
        }
        __syncthreads();
        asm volatile("" ::: "memory");
    };

    __syncthreads();   // wt2s init GLLs drained (syncthreads waits vmcnt)

    for (int r = 0; r <= SEQ; ++r) {
        const __hip_bfloat16* h1p = ((r-1)&1) ? h1b : h1a;   // h1[r-1]
        __hip_bfloat16*       h1c = (r&1)     ? h1b : h1a;   // h1[r]
        const __hip_bfloat16* h2c = (r&1)     ? h2b : h2a;   // h2[r-2]
        __hip_bfloat16*       h2p = ((r-1)&1) ? h2b : h2a;   // h2[r-1]
        const __hip_bfloat16* h1base = h1p + (size_t)m0g*HU;
        const __hip_bfloat16* h2base = h2c + (size_t)m0g*HU;

        if (r < SEQ) {
            // ---- Layer 1: t=r, K=640 (embp 0..127 | h1p 128..639), 20 tiles ----
            const int id0 = ids[(m0g + (w*2  )*16 + l15)*SEQ + r];
            const int id1 = ids[(m0g + (w*2+1)*16 + l15)*SEQ + r];
            zacc();
            stageA_emb(id0, id1, 0, 0);
            stageBt(wt1, 640, 0, 0);
            __syncthreads();
            #pragma unroll
            for (int i = 0; i < 20; ++i) {
                const int b = i & 1;
                if (i < 19) {
                    const int k = (i+1)*32;
                    if (k < 128) stageA_emb(id0, id1, k, b^1);
                    else         stageA(h1base, k - 128, b^1, true);
                    stageBt(wt1, 640, k, b^1);
                }
                compute(stgA(b), stgB(b));
                __syncthreads();
            }
            epilogue(bp1, c1r, h1c);
        }

        if (r >= 1) {
            // ---- Layer 2: t=r-1, K=1024 (h1p 0..511 | h2c 512..1023), 32 tiles ----
            zacc();
            stageA(h1base, 0, 0, true);
            __syncthreads();
            #pragma unroll
            for (int i = 0; i < 32; ++i) {
                const int b = i & 1;
                if (i < 31) {
                    const int k = (i+1)*32;
                    if (k < 512) stageA(h1base, k, b^1, true);
                    else         stageA(h2base, k - 512, b^1, true);
                    if (k >= 896) stageBt(wt2, 1024, k, b^1);   // streamed tail
                }
                const char* Bb = (i < 28) ? (wt2s_ + i*4096) : stgB(b);
                compute(stgA(b), Bb);
                __syncthreads();
            }
            epilogue(bp2, c2r, h2p);
        }
        bar();
    }
}

// out[b] = sigmoid(h2[b,:] @ Wd + bd)
__global__ __launch_bounds__(256) void head_k(const __hip_bfloat16* __restrict__ h2,
    const float* __restrict__ Wd, const float* __restrict__ bd, float* __restrict__ out)
{
    const int b = blockIdx.x*4 + (threadIdx.x >> 6);
    const int lane = threadIdx.x & 63;
    float s = 0.f;
    #pragma unroll
    for (int u = lane; u < HU; u += 64) s += __bfloat162float(h2[b*HU + u]) * Wd[u];
    #pragma unroll
    for (int off = 32; off > 0; off >>= 1) s += __shfl_xor(s, off);
    if (lane == 0) out[b] = 1.f/(1.f + __expf(-(s + bd[0])));
}

extern "C" void kernel_launch(void* const* d_in, const int* in_sizes, int n_in,
                              void* d_out, int out_size, void* d_ws, size_t ws_size,
                              hipStream_t stream)
{
    const int*   ids = (const int*)  d_in[0];
    const float* emb = (const float*)d_in[1];
    const float* W1  = (const float*)d_in[2];
    const float* U1  = (const float*)d_in[3];
    const float* b1  = (const float*)d_in[4];
    const float* W2  = (const float*)d_in[5];
    const float* U2  = (const float*)d_in[6];
    const float* b2  = (const float*)d_in[7];
    const float* Wd  = (const float*)d_in[8];
    const float* bd  = (const float*)d_in[9];
    float* out = (float*)d_out;

    const size_t HS = (size_t)BATCH*HU;
    char* p = (char*)d_ws;
    unsigned long long* xbars = (unsigned long long*)p;        // 8 x 64B apart
    unsigned*           slotc = (unsigned*)(p + 512);          // 8
    p += 1024;
    __hip_bfloat16* h1a = (__hip_bfloat16*)p;  p += HS*2;
    __hip_bfloat16* h1b = (__hip_bfloat16*)p;  p += HS*2;
    __hip_bfloat16* h2a = (__hip_bfloat16*)p;  p += HS*2;
    __hip_bfloat16* h2b = (__hip_bfloat16*)p;  p += HS*2;
    __hip_bfloat16* embp = (__hip_bfloat16*)p; p += (size_t)10000*128*2;
    __hip_bfloat16* wt1  = (__hip_bfloat16*)p; p += (size_t)2048*640*2;
    __hip_bfloat16* wt2  = (__hip_bfloat16*)p; p += (size_t)2048*1024*2;
    float* bp1 = (float*)p;                    p += 2048*4;
    float* bp2 = (float*)p;                    p += 2048*4;

    // zero barriers + slot counters + all h buffers (replay-safe, deterministic)
    hipMemsetAsync(d_ws, 0, 1024 + 4*HS*2, stream);

    prep_emb<<<10000*128/256, 256, 0, stream>>>(emb, embp);
    prep_wt<<<dim3(2048,2), 256, 0, stream>>>(W1,U1,b1,W2,U2,b2, wt1,wt2,bp1,bp2);

    lstm_persist<<<256, 512, 0, stream>>>(ids, embp, wt1, bp1, wt2, bp2,
                                          h1a, h1b, h2a, h2b, xbars, slotc);

    // h2[t=79] written at r=80 into h2[(80-1)&1] = h2b
    head_k<<<BATCH/4, 256, 0, stream>>>(h2b, Wd, bd, out);
}

// Round 9
// 3640.190 us; speedup vs baseline: 3.0796x; 1.1960x over previous
//
#include <hip/hip_runtime.h>
#include <hip/hip_bf16.h>

#define BATCH 2048
#define SEQ   80
#define EMBD  100
#define HU    512
#define NG    2048

typedef short bf16x8 __attribute__((ext_vector_type(8)));
typedef float f32x4  __attribute__((ext_vector_type(4)));
typedef int   i32x4  __attribute__((ext_vector_type(4)));

#define AS1(p) ((const __attribute__((address_space(1))) void*)(p))
#define AS3(p) ((__attribute__((address_space(3))) void*)(p))
#define GLL(src, dst, aux) __builtin_amdgcn_global_load_lds(AS1(src), AS3(dst), 16, 0, aux)

// ---------------- prep kernels (proven, unchanged) ----------------
__global__ __launch_bounds__(256) void prep_emb(const float* __restrict__ emb,
                                                __hip_bfloat16* __restrict__ embp)
{
    int idx = blockIdx.x*256 + threadIdx.x;
    int row = idx >> 7, k = idx & 127;
    embp[idx] = __float2bfloat16(k < EMBD ? emb[row*EMBD + k] : 0.f);
}

// Gate-interleaved transposed weights. n = u*4 + g, col_orig = g*512 + u.
__global__ __launch_bounds__(256) void prep_wt(
    const float* __restrict__ W1, const float* __restrict__ U1, const float* __restrict__ b1,
    const float* __restrict__ W2, const float* __restrict__ U2, const float* __restrict__ b2,
    __hip_bfloat16* __restrict__ wt1, __hip_bfloat16* __restrict__ wt2,
    float* __restrict__ bp1, float* __restrict__ bp2)
{
    const int n = blockIdx.x;
    const int u = n >> 2, g = n & 3, col = g*HU + u;
    if (blockIdx.y == 0) {
        for (int k = threadIdx.x; k < 640; k += 256) {
            float v = (k < EMBD) ? W1[k*NG + col] : ((k < 128) ? 0.f : U1[(k-128)*NG + col]);
            wt1[n*640 + k] = __float2bfloat16(v);
        }
        if (threadIdx.x == 0) bp1[n] = b1[col];
    } else {
        for (int k = threadIdx.x; k < 1024; k += 256) {
            float v = (k < HU) ? W2[k*NG + col] : U2[(k-HU)*NG + col];
            wt2[n*1024 + k] = __float2bfloat16(v);
        }
        if (threadIdx.x == 0) bp2[n] = b2[col];
    }
}

// ---------------- persistent LSTM: XCD batch-split + counted-vmcnt pipeline ----------------
// XCD x owns rows [256x,256x+256). 32 blocks/XCD: mb(2 row-halves) x nb(16 col-groups),
// block tile 128 rows x 128 gate-cols. 8 waves = 2M(64r) x 4N(32c). BK=64.
// K-loop: 4-buffer LDS ring, 3 tiles in flight, s_waitcnt vmcnt(8) + raw s_barrier
// per tile (never drain to 0 mid-loop). h coherence: plain store -> own-XCD L2,
// read via GLL aux=1 (sc0, L1 bypass). One XCD-local barrier per round.
__global__ __launch_bounds__(512, 1) void lstm_persist(
    const int* __restrict__ ids,
    const __hip_bfloat16* __restrict__ embp,
    const __hip_bfloat16* __restrict__ wt1, const float* __restrict__ bp1,
    const __hip_bfloat16* __restrict__ wt2, const float* __restrict__ bp2,
    __hip_bfloat16* __restrict__ h1a, __hip_bfloat16* __restrict__ h1b,
    __hip_bfloat16* __restrict__ h2a, __hip_bfloat16* __restrict__ h2b,
    unsigned long long* __restrict__ xbars,   // [8] spaced 64B
    unsigned* __restrict__ slotctr)           // [8]
{
    __shared__ __align__(16) char ring[4][32768];        // A 16KB | B 16KB per buf
    __shared__ __align__(16) unsigned short hsp[128*32]; // 8KB h-out stage
    __shared__ int s_info;

    const int tid = threadIdx.x;
    if (tid == 0) {
        unsigned x = __builtin_amdgcn_s_getreg(63508) & 7u;   // HW_REG_XCC_ID
        unsigned s = atomicAdd(&slotctr[x], 1u);
        s_info = (int)((x << 8) | (s & 31u));
    }
    __syncthreads();
    const int xcd  = (s_info >> 8) & 7;
    const int slot = s_info & 31;
    const int mb = slot >> 4, nb = slot & 15;
    const int m0g = xcd*256 + mb*128;    // batch-row base (XCD-local)
    const int n0  = nb*128;              // gate-col base

    const int w = tid >> 6, lane = tid & 63;
    const int l15 = lane & 15, tq = lane >> 4;
    const int wM = w >> 2, wN = w & 3;   // wave tile: rows wM*64+, cols wN*32+
    const int rowA = w*16 + l15;         // block-local row this lane stages (A and B)

    unsigned long long* xb = &xbars[xcd*8];

    f32x4 acc[4][2];
    float c1r[4][2][4] = {};             // cell state (live on gq==1 lanes)
    float c2r[4][2][4] = {};

    auto zacc = [&](){
        #pragma unroll
        for (int mi = 0; mi < 4; ++mi)
            #pragma unroll
            for (int ni = 0; ni < 2; ++ni) acc[mi][ni] = (f32x4){0.f,0.f,0.f,0.f};
    };

    auto compute = [&](const char* buf){
        #pragma unroll
        for (int s = 0; s < 2; ++s) {
            bf16x8 aF[4], bF[2];
            #pragma unroll
            for (int mi = 0; mi < 4; ++mi)
                aF[mi] = *(const bf16x8*)(buf + (wM*4+mi)*2048 + s*1024 + tq*256 + l15*16);
            #pragma unroll
            for (int ni = 0; ni < 2; ++ni)
                bF[ni] = *(const bf16x8*)(buf + 16384 + (wN*2+ni)*2048 + s*1024 + tq*256 + l15*16);
            #pragma unroll
            for (int mi = 0; mi < 4; ++mi)
                #pragma unroll
                for (int ni = 0; ni < 2; ++ni)
                    acc[mi][ni] = __builtin_amdgcn_mfma_f32_16x16x32_bf16(
                                      aF[mi], bF[ni], acc[mi][ni], 0, 0, 0);
        }
    };

    // gates epilogue: 4-lane group = {i,f,g,o} of one unit; c in regs; h via LDS stage
    auto epilogue = [&](const float* bp, float (&cr)[4][2][4], __hip_bfloat16* hdst){
        const int gq = l15 & 3;
        const bool isT = (gq == 2);
        #pragma unroll
        for (int ni = 0; ni < 2; ++ni) {
            const int nl = wN*32 + ni*16 + l15;
            const float bv = bp[n0 + nl];
            const int ul = nl >> 2;
            #pragma unroll
            for (int mi = 0; mi < 4; ++mi) {
                #pragma unroll
                for (int rr = 0; rr < 4; ++rr) {
                    const int rowl = wM*64 + mi*16 + tq*4 + rr;
                    const float z  = acc[mi][ni][rr] + bv;
                    const float zz = isT ? 2.f*z : z;
                    const float sg = 1.f/(1.f + __expf(-zz));
                    const float act = isT ? fmaf(2.f, sg, -1.f) : sg;   // tanh via sigm
                    const float act2 = __shfl_xor(act, 2);    // i<->g, f<->o
                    const float pig  = act * act2;            // gq0: sig(i)*tanh(g)
                    const float pig1 = __shfl_xor(pig, 1);    // gq1 <- gq0
                    const float cn  = fmaf(act, cr[mi][ni][rr], pig1);  // gq1
                    const float tcn = fmaf(2.f, 1.f/(1.f + __expf(-2.f*cn)), -1.f);
                    const float tcn2 = __shfl_xor(tcn, 2);    // gq3 <- gq1
                    const float hv  = act * tcn2;             // gq3: sig(o)*tanh(c)
                    if (gq == 1) cr[mi][ni][rr] = cn;
                    if (gq == 3) {
                        __hip_bfloat16 hb = __float2bfloat16(hv);
                        hsp[rowl*32 + ul] = *(unsigned short*)&hb;
                    }
                }
            }
        }
        __syncthreads();
        {   // 8KB h slice -> global plain store (lands in own-XCD L2)
            const int row = tid >> 2, uo = (tid & 3)*8;
            i32x4 v = *(const i32x4*)(hsp + row*32 + uo);
            *(i32x4*)(hdst + (size_t)(m0g + row)*HU + (n0 >> 2) + uo) = v;
        }
        __syncthreads();
    };

    // XCD-local barrier (32 blocks), relaxed u64 {gen,cnt} — no cache maintenance
    auto bar = [&](){
        asm volatile("s_waitcnt vmcnt(0)" ::: "memory");
        __syncthreads();
        if (tid == 0) {
            unsigned long long old = __hip_atomic_fetch_add(xb, 1ull,
                                        __ATOMIC_RELAXED, __HIP_MEMORY_SCOPE_AGENT);
            unsigned g = (unsigned)(old >> 32);
            if ((unsigned)(old & 0xffffffffull) == 31u)
                __hip_atomic_fetch_add(xb, (1ull << 32) - 32ull,
                                       __ATOMIC_RELAXED, __HIP_MEMORY_SCOPE_AGENT);
            else
                while ((unsigned)(__hip_atomic_load(xb, __ATOMIC_RELAXED,
                                        __HIP_MEMORY_SCOPE_AGENT) >> 32) == g)
                    __builtin_amdgcn_s_sleep(2);
        }
        __syncthreads();
        asm volatile("" ::: "memory");
    };

    for (int r = 0; r <= SEQ; ++r) {
        const __hip_bfloat16* h1p = ((r-1)&1) ? h1b : h1a;   // h1[r-1]
        __hip_bfloat16*       h1c = (r&1)     ? h1b : h1a;   // h1[r]
        const __hip_bfloat16* h2c = (r&1)     ? h2b : h2a;   // h2[r-2]
        __hip_bfloat16*       h2p = ((r-1)&1) ? h2b : h2a;   // h2[r-1]

        if (r < SEQ) {
            // ---- Layer 1: t=r, K=640 (embp k<128 | h1p k>=128), 10 tiles of 64 ----
            const int myid = ids[(m0g + rowA)*SEQ + r];
            const __hip_bfloat16* eb = embp + (size_t)myid*128 + tq*8;
            const __hip_bfloat16* ha = h1p + (size_t)(m0g + rowA)*HU + tq*8;
            const __hip_bfloat16* wb = wt1 + (size_t)(n0 + rowA)*640 + tq*8;
            zacc();

            #define STG1(kt, buf) {                                              \
                char* A0 = ring[buf] + w*2048;                                   \
                char* B0 = ring[buf] + 16384 + w*2048;                           \
                _Pragma("unroll")                                                \
                for (int hf = 0; hf < 2; ++hf) {                                 \
                    const int k = (kt)*64 + hf*32;                               \
                    if ((kt) < 2) GLL(eb + k,         A0 + hf*1024, 0);          \
                    else          GLL(ha + (k - 128), A0 + hf*1024, 1);          \
                    GLL(wb + k, B0 + hf*1024, 0);                                \
                } }

            STG1(0, 0) STG1(1, 1) STG1(2, 2)
            #pragma unroll
            for (int i = 0; i < 10; ++i) {
                if (i < 8)       asm volatile("s_waitcnt vmcnt(8)" ::: "memory");
                else if (i == 8) asm volatile("s_waitcnt vmcnt(4)" ::: "memory");
                else             asm volatile("s_waitcnt vmcnt(0)" ::: "memory");
                __builtin_amdgcn_s_barrier();
                __builtin_amdgcn_sched_barrier(0);
                if (i + 3 < 10) STG1(i + 3, (i + 3) & 3)
                compute(ring[i & 3]);
            }
            #undef STG1
            epilogue(bp1, c1r, h1c);
        }

        if (r >= 1) {
            // ---- Layer 2: t=r-1, K=1024 (h1p k<512 | h2c k>=512), 16 tiles of 64 ----
            const __hip_bfloat16* ha = h1p + (size_t)(m0g + rowA)*HU + tq*8;
            const __hip_bfloat16* hb = h2c + (size_t)(m0g + rowA)*HU + tq*8;
            const __hip_bfloat16* wb = wt2 + (size_t)(n0 + rowA)*1024 + tq*8;
            zacc();

            #define STG2(kt, buf) {                                              \
                char* A0 = ring[buf] + w*2048;                                   \
                char* B0 = ring[buf] + 16384 + w*2048;                           \
                _Pragma("unroll")                                                \
                for (int hf = 0; hf < 2; ++hf) {                                 \
                    const int k = (kt)*64 + hf*32;                               \
                    if (k < 512) GLL(ha + k,         A0 + hf*1024, 1);           \
                    else         GLL(hb + (k - 512), A0 + hf*1024, 1);           \
                    GLL(wb + k, B0 + hf*1024, 0);                                \
                } }

            STG2(0, 0) STG2(1, 1) STG2(2, 2)
            #pragma unroll
            for (int i = 0; i < 16; ++i) {
                if (i < 14)       asm volatile("s_waitcnt vmcnt(8)" ::: "memory");
                else if (i == 14) asm volatile("s_waitcnt vmcnt(4)" ::: "memory");
                else              asm volatile("s_waitcnt vmcnt(0)" ::: "memory");
                __builtin_amdgcn_s_barrier();
                __builtin_amdgcn_sched_barrier(0);
                if (i + 3 < 16) STG2(i + 3, (i + 3) & 3)
                compute(ring[i & 3]);
            }
            #undef STG2
            epilogue(bp2, c2r, h2p);
        }
        bar();
    }
}

// out[b] = sigmoid(h2[b,:] @ Wd + bd)
__global__ __launch_bounds__(256) void head_k(const __hip_bfloat16* __restrict__ h2,
    const float* __restrict__ Wd, const float* __restrict__ bd, float* __restrict__ out)
{
    const int b = blockIdx.x*4 + (threadIdx.x >> 6);
    const int lane = threadIdx.x & 63;
    float s = 0.f;
    #pragma unroll
    for (int u = lane; u < HU; u += 64) s += __bfloat162float(h2[b*HU + u]) * Wd[u];
    #pragma unroll
    for (int off = 32; off > 0; off >>= 1) s += __shfl_xor(s, off);
    if (lane == 0) out[b] = 1.f/(1.f + __expf(-(s + bd[0])));
}

extern "C" void kernel_launch(void* const* d_in, const int* in_sizes, int n_in,
                              void* d_out, int out_size, void* d_ws, size_t ws_size,
                              hipStream_t stream)
{
    const int*   ids = (const int*)  d_in[0];
    const float* emb = (const float*)d_in[1];
    const float* W1  = (const float*)d_in[2];
    const float* U1  = (const float*)d_in[3];
    const float* b1  = (const float*)d_in[4];
    const float* W2  = (const float*)d_in[5];
    const float* U2  = (const float*)d_in[6];
    const float* b2  = (const float*)d_in[7];
    const float* Wd  = (const float*)d_in[8];
    const float* bd  = (const float*)d_in[9];
    float* out = (float*)d_out;

    const size_t HS = (size_t)BATCH*HU;
    char* p = (char*)d_ws;
    unsigned long long* xbars = (unsigned long long*)p;        // 8 x 64B apart
    unsigned*           slotc = (unsigned*)(p + 512);          // 8
    p += 1024;
    __hip_bfloat16* h1a = (__hip_bfloat16*)p;  p += HS*2;
    __hip_bfloat16* h1b = (__hip_bfloat16*)p;  p += HS*2;
    __hip_bfloat16* h2a = (__hip_bfloat16*)p;  p += HS*2;
    __hip_bfloat16* h2b = (__hip_bfloat16*)p;  p += HS*2;
    __hip_bfloat16* embp = (__hip_bfloat16*)p; p += (size_t)10000*128*2;
    __hip_bfloat16* wt1  = (__hip_bfloat16*)p; p += (size_t)2048*640*2;
    __hip_bfloat16* wt2  = (__hip_bfloat16*)p; p += (size_t)2048*1024*2;
    float* bp1 = (float*)p;                    p += 2048*4;
    float* bp2 = (float*)p;                    p += 2048*4;

    // zero barriers + slot counters + all h buffers (replay-safe, deterministic)
    hipMemsetAsync(d_ws, 0, 1024 + 4*HS*2, stream);

    prep_emb<<<10000*128/256, 256, 0, stream>>>(emb, embp);
    prep_wt<<<dim3(2048,2), 256, 0, stream>>>(W1,U1,b1,W2,U2,b2, wt1,wt2,bp1,bp2);

    lstm_persist<<<256, 512, 0, stream>>>(ids, embp, wt1, bp1, wt2, bp2,
                                          h1a, h1b, h2a, h2b, xbars, slotc);

    // h2[t=79] written at r=80 into h2[(80-1)&1] = h2b
    head_k<<<BATCH/4, 256, 0, stream>>>(h2b, Wd, bd, out);
}

// Round 10
// 2855.422 us; speedup vs baseline: 3.9260x; 1.2748x over previous
//
#include <hip/hip_runtime.h>
#include <hip/hip_bf16.h>

#define BATCH 2048
#define SEQ   80
#define EMBD  100
#define HU    512
#define NG    2048

typedef short bf16x8 __attribute__((ext_vector_type(8)));
typedef float f32x4  __attribute__((ext_vector_type(4)));
typedef int   i32x2  __attribute__((ext_vector_type(2)));

#define AS1(p) ((const __attribute__((address_space(1))) void*)(p))
#define AS3(p) ((__attribute__((address_space(3))) void*)(p))
#define GLL(src, dst, aux) __builtin_amdgcn_global_load_lds(AS1(src), AS3(dst), 16, 0, aux)

// ---------------- prep kernels (proven, unchanged) ----------------
__global__ __launch_bounds__(256) void prep_emb(const float* __restrict__ emb,
                                                __hip_bfloat16* __restrict__ embp)
{
    int idx = blockIdx.x*256 + threadIdx.x;
    int row = idx >> 7, k = idx & 127;
    embp[idx] = __float2bfloat16(k < EMBD ? emb[row*EMBD + k] : 0.f);
}

// Gate-interleaved transposed weights. n = u*4 + g, col_orig = g*512 + u.
__global__ __launch_bounds__(256) void prep_wt(
    const float* __restrict__ W1, const float* __restrict__ U1, const float* __restrict__ b1,
    const float* __restrict__ W2, const float* __restrict__ U2, const float* __restrict__ b2,
    __hip_bfloat16* __restrict__ wt1, __hip_bfloat16* __restrict__ wt2,
    float* __restrict__ bp1, float* __restrict__ bp2)
{
    const int n = blockIdx.x;
    const int u = n >> 2, g = n & 3, col = g*HU + u;
    if (blockIdx.y == 0) {
        for (int k = threadIdx.x; k < 640; k += 256) {
            float v = (k < EMBD) ? W1[k*NG + col] : ((k < 128) ? 0.f : U1[(k-128)*NG + col]);
            wt1[n*640 + k] = __float2bfloat16(v);
        }
        if (threadIdx.x == 0) bp1[n] = b1[col];
    } else {
        for (int k = threadIdx.x; k < 1024; k += 256) {
            float v = (k < HU) ? W2[k*NG + col] : U2[(k-HU)*NG + col];
            wt2[n*1024 + k] = __float2bfloat16(v);
        }
        if (threadIdx.x == 0) bp2[n] = b2[col];
    }
}

// ---------------- persistent LSTM: XCD batch-split, 16 waves, counted-vmcnt ----------------
// 256 blocks x 1024 thr (16 waves = 4/SIMD). XCD x owns rows [256x,256x+256);
// slot -> mb(2) x nb(16), block tile 128r x 128c, waves 32x32 (wM=w>>2, wN=w&3).
// BK=64, ring4, 3 tiles in flight, per-tile s_waitcnt vmcnt(4) + raw s_barrier.
// Epilogue: acc -> LDS transpose -> per-thread 4 units (gate-interleaved f32x4),
// shuffle-free gate math, c in 8 regs, direct coalesced h store.
__global__ __launch_bounds__(1024, 4) void lstm_persist(
    const int* __restrict__ ids,
    const __hip_bfloat16* __restrict__ embp,
    const __hip_bfloat16* __restrict__ wt1, const float* __restrict__ bp1,
    const __hip_bfloat16* __restrict__ wt2, const float* __restrict__ bp2,
    __hip_bfloat16* __restrict__ h1a, __hip_bfloat16* __restrict__ h1b,
    __hip_bfloat16* __restrict__ h2a, __hip_bfloat16* __restrict__ h2b,
    unsigned long long* __restrict__ xbars,   // [8] spaced 64B
    unsigned* __restrict__ slotctr)           // [8]
{
    __shared__ __align__(16) char ring[4][32768];   // A 16KB | B 16KB per buf (128KB)
    __shared__ int s_info;
    float* rp = (float*)&ring[0][0];                // epilogue overlay [128][132] f32

    const int tid = threadIdx.x;
    if (tid == 0) {
        unsigned x = __builtin_amdgcn_s_getreg(63508) & 7u;   // HW_REG_XCC_ID
        unsigned s = atomicAdd(&slotctr[x], 1u);
        s_info = (int)((x << 8) | (s & 31u));
    }
    __syncthreads();
    const int xcd  = (s_info >> 8) & 7;
    const int slot = s_info & 31;
    const int mb = slot >> 4, nb = slot & 15;
    const int m0g = xcd*256 + mb*128;    // batch-row base (XCD-local)
    const int n0  = nb*128;              // gate-col base

    const int w = tid >> 6, lane = tid & 63;
    const int l15 = lane & 15, tq = lane >> 4;
    const int wM = w >> 2, wN = w & 3;   // wave tile: rows wM*32+, cols wN*32+
    const int khw = w >> 3;              // staging k-half role
    const int rowA = (w & 7)*16 + l15;   // block-local row/col this lane stages
    const int growA = m0g + rowA;
    const int colB = n0 + rowA;
    const int erow = tid >> 3;           // epilogue: owned row 0..127
    const int eu8  = tid & 7;            // epilogue: unit group (4 units)

    unsigned long long* xb = &xbars[xcd*8];

    f32x4 acc[2][2];
    float c1r[4] = {0.f,0.f,0.f,0.f};    // cell state, thread-owned (row, 4 units)
    float c2r[4] = {0.f,0.f,0.f,0.f};

    auto zacc = [&](){
        #pragma unroll
        for (int mi = 0; mi < 2; ++mi)
            #pragma unroll
            for (int ni = 0; ni < 2; ++ni) acc[mi][ni] = (f32x4){0.f,0.f,0.f,0.f};
    };

    auto compute = [&](int buf){
        const char* base = &ring[buf][0];
        __builtin_amdgcn_s_setprio(1);
        #pragma unroll
        for (int s = 0; s < 2; ++s) {
            bf16x8 aF[2], bF[2];
            #pragma unroll
            for (int mi = 0; mi < 2; ++mi)
                aF[mi] = *(const bf16x8*)(base + (s*8 + wM*2 + mi)*1024 + tq*256 + l15*16);
            #pragma unroll
            for (int ni = 0; ni < 2; ++ni)
                bF[ni] = *(const bf16x8*)(base + 16384 + (s*8 + wN*2 + ni)*1024 + tq*256 + l15*16);
            #pragma unroll
            for (int mi = 0; mi < 2; ++mi)
                #pragma unroll
                for (int ni = 0; ni < 2; ++ni)
                    acc[mi][ni] = __builtin_amdgcn_mfma_f32_16x16x32_bf16(
                                      aF[mi], bF[ni], acc[mi][ni], 0, 0, 0);
        }
        __builtin_amdgcn_s_setprio(0);
    };

    // shuffle-free epilogue: acc -> rp (LDS) -> each thread: 4 gate-interleaved units
    auto epilogue = [&](const float* bp, float* cr, __hip_bfloat16* hdst){
        __syncthreads();   // all computes done -> ring free for rp overlay
        #pragma unroll
        for (int mi = 0; mi < 2; ++mi)
            #pragma unroll
            for (int ni = 0; ni < 2; ++ni)
                #pragma unroll
                for (int rr = 0; rr < 4; ++rr)
                    rp[(wM*32 + mi*16 + tq*4 + rr)*132 + wN*32 + ni*16 + l15] = acc[mi][ni][rr];
        __syncthreads();
        unsigned hw[4];
        #pragma unroll
        for (int j = 0; j < 4; ++j) {
            const int ul = eu8*4 + j;                         // local unit 0..31
            f32x4 z  = *(const f32x4*)&rp[erow*132 + ul*4];   // gates i,f,g,o of unit
            f32x4 bb = *(const f32x4*)(bp + n0 + ul*4);
            const float gi = 1.f/(1.f + __expf(-(z[0] + bb[0])));
            const float gf = 1.f/(1.f + __expf(-(z[1] + bb[1])));
            const float gg = fmaf(2.f, 1.f/(1.f + __expf(-2.f*(z[2] + bb[2]))), -1.f);
            const float go = 1.f/(1.f + __expf(-(z[3] + bb[3])));
            const float cn = fmaf(gf, cr[j], gi*gg);
            cr[j] = cn;
            const float tc = fmaf(2.f, 1.f/(1.f + __expf(-2.f*cn)), -1.f);
            const float hv = go*tc;
            __hip_bfloat16 hb = __float2bfloat16(hv);
            hw[j] = (unsigned)*(const unsigned short*)&hb;
        }
        i32x2 v;
        v[0] = (int)(hw[0] | (hw[1] << 16));
        v[1] = (int)(hw[2] | (hw[3] << 16));
        *(i32x2*)(hdst + (size_t)(m0g + erow)*HU + (n0 >> 2) + eu8*4) = v;  // own-XCD L2
        __syncthreads();   // rp reads done before ring reuse
    };

    // XCD-local barrier (32 blocks), relaxed u64 {gen,cnt} — no cache maintenance
    auto bar = [&](){
        asm volatile("s_waitcnt vmcnt(0)" ::: "memory");
        __syncthreads();
        if (tid == 0) {
            unsigned long long old = __hip_atomic_fetch_add(xb, 1ull,
                                        __ATOMIC_RELAXED, __HIP_MEMORY_SCOPE_AGENT);
            unsigned g = (unsigned)(old >> 32);
            if ((unsigned)(old & 0xffffffffull) == 31u)
                __hip_atomic_fetch_add(xb, (1ull << 32) - 32ull,
                                       __ATOMIC_RELAXED, __HIP_MEMORY_SCOPE_AGENT);
            else
                while ((unsigned)(__hip_atomic_load(xb, __ATOMIC_RELAXED,
                                        __HIP_MEMORY_SCOPE_AGENT) >> 32) == g)
                    __builtin_amdgcn_s_sleep(2);
        }
        __syncthreads();
        asm volatile("" ::: "memory");
    };

    for (int r = 0; r <= SEQ; ++r) {
        const __hip_bfloat16* h1p = ((r-1)&1) ? h1b : h1a;   // h1[r-1]
        __hip_bfloat16*       h1c = (r&1)     ? h1b : h1a;   // h1[r]
        const __hip_bfloat16* h2c = (r&1)     ? h2b : h2a;   // h2[r-2]
        __hip_bfloat16*       h2p = ((r-1)&1) ? h2b : h2a;   // h2[r-1]
        const __hip_bfloat16* ha1 = h1p + (size_t)growA*HU + tq*8;
        const __hip_bfloat16* ha2 = h2c + (size_t)growA*HU + tq*8;

        if (r < SEQ) {
            // ---- Layer 1: t=r, K=640 (embp k<128 | h1p k>=128), 10 tiles of 64 ----
            const int myid = ids[growA*SEQ + r];
            const __hip_bfloat16* eb = embp + (size_t)myid*128 + tq*8;
            const __hip_bfloat16* wb = wt1 + (size_t)colB*640 + tq*8;
            zacc();

            auto stage1 = [&](int kt, int buf){
                const int k0 = kt*64 + khw*32;
                if (k0 < 128) GLL(eb + k0,          &ring[buf][w*1024], 0);
                else          GLL(ha1 + (k0 - 128), &ring[buf][w*1024], 1);
                GLL(wb + k0, &ring[buf][16384 + w*1024], 0);
            };

            stage1(0, 0); stage1(1, 1); stage1(2, 2);
            #pragma unroll
            for (int i = 0; i < 10; ++i) {
                if (i < 8)       asm volatile("s_waitcnt vmcnt(4)" ::: "memory");
                else if (i == 8) asm volatile("s_waitcnt vmcnt(2)" ::: "memory");
                else             asm volatile("s_waitcnt vmcnt(0)" ::: "memory");
                __builtin_amdgcn_s_barrier();
                __builtin_amdgcn_sched_barrier(0);
                if (i + 3 < 10) stage1(i + 3, (i + 3) & 3);
                compute(i & 3);
            }
            epilogue(bp1, c1r, h1c);
        }

        if (r >= 1) {
            // ---- Layer 2: t=r-1, K=1024 (h1p k<512 | h2c k>=512), 16 tiles of 64 ----
            const __hip_bfloat16* wb = wt2 + (size_t)colB*1024 + tq*8;
            zacc();

            auto stage2 = [&](int kt, int buf){
                const int k0 = kt*64 + khw*32;
                if (k0 < 512) GLL(ha1 + k0,         &ring[buf][w*1024], 1);
                else          GLL(ha2 + (k0 - 512), &ring[buf][w*1024], 1);
                GLL(wb + k0, &ring[buf][16384 + w*1024], 0);
            };

            stage2(0, 0); stage2(1, 1); stage2(2, 2);
            #pragma unroll
            for (int i = 0; i < 16; ++i) {
                if (i < 14)       asm volatile("s_waitcnt vmcnt(4)" ::: "memory");
                else if (i == 14) asm volatile("s_waitcnt vmcnt(2)" ::: "memory");
                else              asm volatile("s_waitcnt vmcnt(0)" ::: "memory");
                __builtin_amdgcn_s_barrier();
                __builtin_amdgcn_sched_barrier(0);
                if (i + 3 < 16) stage2(i + 3, (i + 3) & 3);
                compute(i & 3);
            }
            epilogue(bp2, c2r, h2p);
        }
        bar();
    }
}

// out[b] = sigmoid(h2[b,:] @ Wd + bd)
__global__ __launch_bounds__(256) void head_k(const __hip_bfloat16* __restrict__ h2,
    const float* __restrict__ Wd, const float* __restrict__ bd, float* __restrict__ out)
{
    const int b = blockIdx.x*4 + (threadIdx.x >> 6);
    const int lane = threadIdx.x & 63;
    float s = 0.f;
    #pragma unroll
    for (int u = lane; u < HU; u += 64) s += __bfloat162float(h2[b*HU + u]) * Wd[u];
    #pragma unroll
    for (int off = 32; off > 0; off >>= 1) s += __shfl_xor(s, off);
    if (lane == 0) out[b] = 1.f/(1.f + __expf(-(s + bd[0])));
}

extern "C" void kernel_launch(void* const* d_in, const int* in_sizes, int n_in,
                              void* d_out, int out_size, void* d_ws, size_t ws_size,
                              hipStream_t stream)
{
    const int*   ids = (const int*)  d_in[0];
    const float* emb = (const float*)d_in[1];
    const float* W1  = (const float*)d_in[2];
    const float* U1  = (const float*)d_in[3];
    const float* b1  = (const float*)d_in[4];
    const float* W2  = (const float*)d_in[5];
    const float* U2  = (const float*)d_in[6];
    const float* b2  = (const float*)d_in[7];
    const float* Wd  = (const float*)d_in[8];
    const float* bd  = (const float*)d_in[9];
    float* out = (float*)d_out;

    const size_t HS = (size_t)BATCH*HU;
    char* p = (char*)d_ws;
    unsigned long long* xbars = (unsigned long long*)p;        // 8 x 64B apart
    unsigned*           slotc = (unsigned*)(p + 512);          // 8
    p += 1024;
    __hip_bfloat16* h1a = (__hip_bfloat16*)p;  p += HS*2;
    __hip_bfloat16* h1b = (__hip_bfloat16*)p;  p += HS*2;
    __hip_bfloat16* h2a = (__hip_bfloat16*)p;  p += HS*2;
    __hip_bfloat16* h2b = (__hip_bfloat16*)p;  p += HS*2;
    __hip_bfloat16* embp = (__hip_bfloat16*)p; p += (size_t)10000*128*2;
    __hip_bfloat16* wt1  = (__hip_bfloat16*)p; p += (size_t)2048*640*2;
    __hip_bfloat16* wt2  = (__hip_bfloat16*)p; p += (size_t)2048*1024*2;
    float* bp1 = (float*)p;                    p += 2048*4;
    float* bp2 = (float*)p;                    p += 2048*4;

    // zero barriers + slot counters + all h buffers (replay-safe, deterministic)
    hipMemsetAsync(d_ws, 0, 1024 + 4*HS*2, stream);

    prep_emb<<<10000*128/256, 256, 0, stream>>>(emb, embp);
    prep_wt<<<dim3(2048,2), 256, 0, stream>>>(W1,U1,b1,W2,U2,b2, wt1,wt2,bp1,bp2);

    lstm_persist<<<256, 1024, 0, stream>>>(ids, embp, wt1, bp1, wt2, bp2,
                                           h1a, h1b, h2a, h2b, xbars, slotc);

    // h2[t=79] written at r=80 into h2[(80-1)&1] = h2b
    head_k<<<BATCH/4, 256, 0, stream>>>(h2b, Wd, bd, out);
}

// Round 11
// 2730.938 us; speedup vs baseline: 4.1049x; 1.0456x over previous
//
#include <hip/hip_runtime.h>
#include <hip/hip_bf16.h>

#define BATCH 2048
#define SEQ   80
#define EMBD  100
#define HU    512
#define NG    2048

typedef short bf16x8 __attribute__((ext_vector_type(8)));
typedef float f32x4  __attribute__((ext_vector_type(4)));
typedef int   i32x2  __attribute__((ext_vector_type(2)));

#define AS1(p) ((const __attribute__((address_space(1))) void*)(p))
#define AS3(p) ((__attribute__((address_space(3))) void*)(p))
#define GLL(src, dst, aux) __builtin_amdgcn_global_load_lds(AS1(src), AS3(dst), 16, 0, aux)

// B-slot cumulative index per phase: ph 0-1 use 1 B, 2-9 use 2, 10-17 use 1.
__host__ __device__ constexpr int BIdx(int p) {
    return (p <= 1) ? p : ((p <= 9) ? 2 + 2*(p - 2) : 18 + (p - 10));
}

// ---------------- prep kernels (proven, unchanged) ----------------
__global__ __launch_bounds__(256) void prep_emb(const float* __restrict__ emb,
                                                __hip_bfloat16* __restrict__ embp)
{
    int idx = blockIdx.x*256 + threadIdx.x;
    int row = idx >> 7, k = idx & 127;
    embp[idx] = __float2bfloat16(k < EMBD ? emb[row*EMBD + k] : 0.f);
}

// Gate-interleaved transposed weights. n = u*4 + g, col_orig = g*512 + u.
__global__ __launch_bounds__(256) void prep_wt(
    const float* __restrict__ W1, const float* __restrict__ U1, const float* __restrict__ b1,
    const float* __restrict__ W2, const float* __restrict__ U2, const float* __restrict__ b2,
    __hip_bfloat16* __restrict__ wt1, __hip_bfloat16* __restrict__ wt2,
    float* __restrict__ bp1, float* __restrict__ bp2)
{
    const int n = blockIdx.x;
    const int u = n >> 2, g = n & 3, col = g*HU + u;
    if (blockIdx.y == 0) {
        for (int k = threadIdx.x; k < 640; k += 256) {
            float v = (k < EMBD) ? W1[k*NG + col] : ((k < 128) ? 0.f : U1[(k-128)*NG + col]);
            wt1[n*640 + k] = __float2bfloat16(v);
        }
        if (threadIdx.x == 0) bp1[n] = b1[col];
    } else {
        for (int k = threadIdx.x; k < 1024; k += 256) {
            float v = (k < HU) ? W2[k*NG + col] : U2[(k-HU)*NG + col];
            wt2[n*1024 + k] = __float2bfloat16(v);
        }
        if (threadIdx.x == 0) bp2[n] = b2[col];
    }
}

// ---------------- persistent LSTM: XCD batch-split, fused L1+L2 K-loop ----------------
// 256 blocks x 1024 thr (16 waves = 4/SIMD). XCD x owns rows [256x,256x+256);
// slot -> mb(2) x nb(16), block tile 128r x 128c, waves 32x32.
// Per round ONE 18-phase pipeline, two acc sets:
//   ph 0-1 : A=embp  -> acc1 (B=wt1 k 0..127)
//   ph 2-9 : A=h1p   -> acc1 (wt1 k 128..639) AND acc2 (wt2 k 0..511)  [A read once]
//   ph10-17: A=h2c   -> acc2 (wt2 k 512..1023)
// A-ring x3, B-ring x6, depth-2 counted vmcnt (never 0 mid-loop), raw s_barrier.
__global__ __launch_bounds__(1024, 4) void lstm_persist(
    const int* __restrict__ ids,
    const __hip_bfloat16* __restrict__ embp,
    const __hip_bfloat16* __restrict__ wt1, const float* __restrict__ bp1,
    const __hip_bfloat16* __restrict__ wt2, const float* __restrict__ bp2,
    __hip_bfloat16* __restrict__ h1a, __hip_bfloat16* __restrict__ h1b,
    __hip_bfloat16* __restrict__ h2a, __hip_bfloat16* __restrict__ h2b,
    unsigned long long* __restrict__ xbars,   // [8] spaced 64B
    unsigned* __restrict__ slotctr)           // [8]
{
    __shared__ __align__(16) char smem[147456];   // A ring 3x16KB | B ring 6x16KB
    __shared__ int s_info;
    float* rp = (float*)(smem + 49152);           // epilogue overlay [128][132] f32 (68KB<96KB)

    const int tid = threadIdx.x;
    if (tid == 0) {
        unsigned x = __builtin_amdgcn_s_getreg(63508) & 7u;   // HW_REG_XCC_ID
        unsigned s = atomicAdd(&slotctr[x], 1u);
        s_info = (int)((x << 8) | (s & 31u));
    }
    __syncthreads();
    const int xcd  = (s_info >> 8) & 7;
    const int slot = s_info & 31;
    const int mb = slot >> 4, nb = slot & 15;
    const int m0g = xcd*256 + mb*128;    // batch-row base (XCD-local)
    const int n0  = nb*128;              // gate-col base

    const int w = tid >> 6, lane = tid & 63;
    const int l15 = lane & 15, tq = lane >> 4;
    const int wM = w >> 2, wN = w & 3;   // wave tile: rows wM*32+, cols wN*32+
    const int rowA = (w & 7)*16 + l15;   // block-local row/col this lane stages
    const int kL   = (w >> 3)*32 + tq*8; // staging k-offset within a 64-wide phase
    const int growA = m0g + rowA;
    const int colB  = n0 + rowA;
    const int erow = tid >> 3;           // epilogue: owned row 0..127
    const int eu8  = tid & 7;            // epilogue: unit group (4 units)

    unsigned long long* xb = &xbars[xcd*8];

    f32x4 acc1[2][2], acc2[2][2];
    float c1r[4] = {0.f,0.f,0.f,0.f};    // cell state, thread-owned (row, 4 units)
    float c2r[4] = {0.f,0.f,0.f,0.f};

    auto Ab = [&](int p) -> char* { return smem + (((unsigned)p) % 3u)*16384; };
    auto Bq = [&](int bi) -> char* { return smem + 49152 + (((unsigned)bi) % 6u)*16384; };

    // fragment read helper: chunk (s*8 + rowgroup), within: tq*256 + l15*16
    auto frag = [&](const char* base, int s, int g) -> bf16x8 {
        return *(const bf16x8*)(base + (s*8 + g)*1024 + tq*256 + l15*16);
    };

    // shuffle-free epilogue (proven r9): acc -> rp -> per-thread 4 gate-interleaved units
    auto epilogue = [&](f32x4 (&acc)[2][2], const float* bp, float* cr,
                        __hip_bfloat16* hdst, bool wr){
        __syncthreads();
        #pragma unroll
        for (int mi = 0; mi < 2; ++mi)
            #pragma unroll
            for (int ni = 0; ni < 2; ++ni)
                #pragma unroll
                for (int rr = 0; rr < 4; ++rr)
                    rp[(wM*32 + mi*16 + tq*4 + rr)*132 + wN*32 + ni*16 + l15] = acc[mi][ni][rr];
        __syncthreads();
        unsigned hw[4];
        #pragma unroll
        for (int j = 0; j < 4; ++j) {
            const int ul = eu8*4 + j;
            f32x4 z  = *(const f32x4*)&rp[erow*132 + ul*4];
            f32x4 bb = *(const f32x4*)(bp + n0 + ul*4);
            const float gi = 1.f/(1.f + __expf(-(z[0] + bb[0])));
            const float gf = 1.f/(1.f + __expf(-(z[1] + bb[1])));
            const float gg = fmaf(2.f, 1.f/(1.f + __expf(-2.f*(z[2] + bb[2]))), -1.f);
            const float go = 1.f/(1.f + __expf(-(z[3] + bb[3])));
            const float cn = fmaf(gf, cr[j], gi*gg);
            if (wr) cr[j] = cn;
            const float tc = fmaf(2.f, 1.f/(1.f + __expf(-2.f*cn)), -1.f);
            const float hv = go*tc;
            __hip_bfloat16 hb = __float2bfloat16(hv);
            hw[j] = (unsigned)*(const unsigned short*)&hb;
        }
        if (wr) {
            i32x2 v;
            v[0] = (int)(hw[0] | (hw[1] << 16));
            v[1] = (int)(hw[2] | (hw[3] << 16));
            *(i32x2*)(hdst + (size_t)(m0g + erow)*HU + (n0 >> 2) + eu8*4) = v;
        }
        __syncthreads();
    };

    // XCD-local barrier (32 blocks), relaxed u64 {gen,cnt} — no cache maintenance
    auto bar = [&](){
        asm volatile("s_waitcnt vmcnt(0)" ::: "memory");
        __syncthreads();
        if (tid == 0) {
            unsigned long long old = __hip_atomic_fetch_add(xb, 1ull,
                                        __ATOMIC_RELAXED, __HIP_MEMORY_SCOPE_AGENT);
            unsigned g = (unsigned)(old >> 32);
            if ((unsigned)(old & 0xffffffffull) == 31u)
                __hip_atomic_fetch_add(xb, (1ull << 32) - 32ull,
                                       __ATOMIC_RELAXED, __HIP_MEMORY_SCOPE_AGENT);
            else
                while ((unsigned)(__hip_atomic_load(xb, __ATOMIC_RELAXED,
                                        __HIP_MEMORY_SCOPE_AGENT) >> 32) == g)
                    __builtin_amdgcn_s_sleep(2);
        }
        __syncthreads();
        asm volatile("" ::: "memory");
    };

    for (int r = 0; r <= SEQ; ++r) {
        const __hip_bfloat16* h1p = ((r-1)&1) ? h1b : h1a;   // h1[r-1]
        __hip_bfloat16*       h1c = (r&1)     ? h1b : h1a;   // h1[r]
        const __hip_bfloat16* h2c = (r&1)     ? h2b : h2a;   // h2[r-2]
        __hip_bfloat16*       h2p = ((r-1)&1) ? h2b : h2a;   // h2[r-1]

        const int rid = (r < SEQ) ? r : (SEQ - 1);           // avoid OOB ids at r==80
        const int myid = ids[growA*SEQ + rid];
        const __hip_bfloat16* eb  = embp + (size_t)myid*128 + kL;
        const __hip_bfloat16* ha1 = h1p + (size_t)growA*HU + kL;
        const __hip_bfloat16* ha2 = h2c + (size_t)growA*HU + kL;
        const __hip_bfloat16* wb1 = wt1 + (size_t)colB*640 + kL;
        const __hip_bfloat16* wb2 = wt2 + (size_t)colB*1024 + kL;

        auto stage = [&](int p){
            char* Ad = Ab(p) + w*1024;
            if (p < 2) {                 // embp gather + wt1 k 0..127
                GLL(eb + p*64, Ad, 0);
                GLL(wb1 + p*64, Bq(BIdx(p)) + w*1024, 0);
            } else if (p < 10) {         // h1p + wt1[k 128..639] + wt2[k 0..511]
                GLL(ha1 + (p-2)*64, Ad, 1);
                GLL(wb1 + p*64,       Bq(BIdx(p))     + w*1024, 0);
                GLL(wb2 + (p-2)*64,   Bq(BIdx(p) + 1) + w*1024, 0);
            } else {                     // h2c + wt2[k 512..1023]
                GLL(ha2 + (p-10)*64, Ad, 1);
                GLL(wb2 + 512 + (p-10)*64, Bq(BIdx(p)) + w*1024, 0);
            }
        };

        auto compute = [&](int p){
            const char* A = Ab(p);
            __builtin_amdgcn_s_setprio(1);
            #pragma unroll
            for (int s = 0; s < 2; ++s) {
                bf16x8 aF[2];
                #pragma unroll
                for (int mi = 0; mi < 2; ++mi) aF[mi] = frag(A, s, wM*2 + mi);
                if (p < 10) {
                    const char* B1 = Bq(BIdx(p));
                    bf16x8 bF[2];
                    #pragma unroll
                    for (int ni = 0; ni < 2; ++ni) bF[ni] = frag(B1, s, wN*2 + ni);
                    #pragma unroll
                    for (int mi = 0; mi < 2; ++mi)
                        #pragma unroll
                        for (int ni = 0; ni < 2; ++ni)
                            acc1[mi][ni] = __builtin_amdgcn_mfma_f32_16x16x32_bf16(
                                               aF[mi], bF[ni], acc1[mi][ni], 0, 0, 0);
                }
                if (p >= 2) {
                    const char* B2 = (p < 10) ? Bq(BIdx(p) + 1) : Bq(BIdx(p));
                    bf16x8 bF[2];
                    #pragma unroll
                    for (int ni = 0; ni < 2; ++ni) bF[ni] = frag(B2, s, wN*2 + ni);
                    #pragma unroll
                    for (int mi = 0; mi < 2; ++mi)
                        #pragma unroll
                        for (int ni = 0; ni < 2; ++ni)
                            acc2[mi][ni] = __builtin_amdgcn_mfma_f32_16x16x32_bf16(
                                               aF[mi], bF[ni], acc2[mi][ni], 0, 0, 0);
                }
            }
            __builtin_amdgcn_s_setprio(0);
        };

        #pragma unroll
        for (int mi = 0; mi < 2; ++mi)
            #pragma unroll
            for (int ni = 0; ni < 2; ++ni) {
                acc1[mi][ni] = (f32x4){0.f,0.f,0.f,0.f};
                acc2[mi][ni] = (f32x4){0.f,0.f,0.f,0.f};
            }

        stage(0); stage(1);
        #pragma unroll
        for (int p = 0; p < 18; ++p) {
            // counted drain: N = GLL/thread of phase p+1 (2 embp/h2c-phases, 3 h1p-phases)
            if (p == 0)       asm volatile("s_waitcnt vmcnt(2)" ::: "memory");
            else if (p <= 8)  asm volatile("s_waitcnt vmcnt(3)" ::: "memory");
            else if (p <= 16) asm volatile("s_waitcnt vmcnt(2)" ::: "memory");
            else              asm volatile("s_waitcnt vmcnt(0)" ::: "memory");
            __builtin_amdgcn_s_barrier();
            __builtin_amdgcn_sched_barrier(0);
            if (p + 2 < 18) stage(p + 2);
            compute(p);
        }

        epilogue(acc1, bp1, c1r, h1c, r < SEQ);
        epilogue(acc2, bp2, c2r, h2p, r >= 1);
        bar();
    }
}

// out[b] = sigmoid(h2[b,:] @ Wd + bd)
__global__ __launch_bounds__(256) void head_k(const __hip_bfloat16* __restrict__ h2,
    const float* __restrict__ Wd, const float* __restrict__ bd, float* __restrict__ out)
{
    const int b = blockIdx.x*4 + (threadIdx.x >> 6);
    const int lane = threadIdx.x & 63;
    float s = 0.f;
    #pragma unroll
    for (int u = lane; u < HU; u += 64) s += __bfloat162float(h2[b*HU + u]) * Wd[u];
    #pragma unroll
    for (int off = 32; off > 0; off >>= 1) s += __shfl_xor(s, off);
    if (lane == 0) out[b] = 1.f/(1.f + __expf(-(s + bd[0])));
}

extern "C" void kernel_launch(void* const* d_in, const int* in_sizes, int n_in,
                              void* d_out, int out_size, void* d_ws, size_t ws_size,
                              hipStream_t stream)
{
    const int*   ids = (const int*)  d_in[0];
    const float* emb = (const float*)d_in[1];
    const float* W1  = (const float*)d_in[2];
    const float* U1  = (const float*)d_in[3];
    const float* b1  = (const float*)d_in[4];
    const float* W2  = (const float*)d_in[5];
    const float* U2  = (const float*)d_in[6];
    const float* b2  = (const float*)d_in[7];
    const float* Wd  = (const float*)d_in[8];
    const float* bd  = (const float*)d_in[9];
    float* out = (float*)d_out;

    const size_t HS = (size_t)BATCH*HU;
    char* p = (char*)d_ws;
    unsigned long long* xbars = (unsigned long long*)p;        // 8 x 64B apart
    unsigned*           slotc = (unsigned*)(p + 512);          // 8
    p += 1024;
    __hip_bfloat16* h1a = (__hip_bfloat16*)p;  p += HS*2;
    __hip_bfloat16* h1b = (__hip_bfloat16*)p;  p += HS*2;
    __hip_bfloat16* h2a = (__hip_bfloat16*)p;  p += HS*2;
    __hip_bfloat16* h2b = (__hip_bfloat16*)p;  p += HS*2;
    __hip_bfloat16* embp = (__hip_bfloat16*)p; p += (size_t)10000*128*2;
    __hip_bfloat16* wt1  = (__hip_bfloat16*)p; p += (size_t)2048*640*2;
    __hip_bfloat16* wt2  = (__hip_bfloat16*)p; p += (size_t)2048*1024*2;
    float* bp1 = (float*)p;                    p += 2048*4;
    float* bp2 = (float*)p;                    p += 2048*4;

    // zero barriers + slot counters + all h buffers (replay-safe, deterministic)
    hipMemsetAsync(d_ws, 0, 1024 + 4*HS*2, stream);

    prep_emb<<<10000*128/256, 256, 0, stream>>>(emb, embp);
    prep_wt<<<dim3(2048,2), 256, 0, stream>>>(W1,U1,b1,W2,U2,b2, wt1,wt2,bp1,bp2);

    lstm_persist<<<256, 1024, 0, stream>>>(ids, embp, wt1, bp1, wt2, bp2,
                                           h1a, h1b, h2a, h2b, xbars, slotc);

    // h2[t=79] written at r=80 into h2[(80-1)&1] = h2b
    head_k<<<BATCH/4, 256, 0, stream>>>(h2b, Wd, bd, out);
}